// Round 1
// baseline (509.905 us; speedup 1.0000x reference)
//
#include <hip/hip_runtime.h>
#include <hip/hip_bf16.h>

// SemWindowAttention: B=8, H=W=256, C=256, WS=8, NCLS=18
// windows = 8*32*32 = 8192, tokens/window = 64

typedef __bf16 bf16_t;
typedef __bf16 bf16x8 __attribute__((ext_vector_type(8)));
typedef __bf16 bf16x4 __attribute__((ext_vector_type(4)));
typedef float  f32x4  __attribute__((ext_vector_type(4)));

#define MFMA16(a, b, c) __builtin_amdgcn_mfma_f32_16x16x32_bf16((a), (b), (c), 0, 0, 0)

static constexpr int kC = 256, kNCLS = 18;
// ws bf16 layout (element offsets)
static constexpr int WQT_OFF = 0;        // WqT[32][256]  (n-major, zero-padded 18..31)
static constexpr int WKT_OFF = 8192;     // WkT[32][256]
static constexpr int WVT_OFF = 16384;    // WvT[256][256] (WvT[n][k] = Wv[k][n])
static constexpr int WRT_OFF = 81920;    // WresT[256][256]

__global__ __launch_bounds__(256) void prep_weights_kernel(
    const float* __restrict__ Wq, const float* __restrict__ Wk,
    const float* __restrict__ Wv, const float* __restrict__ Wres,
    bf16_t* __restrict__ wsb)
{
  int tid = blockIdx.x * 256 + threadIdx.x;
  if (tid < 8192) {
    int n = tid >> 8, k = tid & 255;
    wsb[tid] = (n < kNCLS) ? (bf16_t)Wq[k * kNCLS + n] : (bf16_t)0.0f;
  } else if (tid < 16384) {
    int t = tid - 8192; int n = t >> 8, k = t & 255;
    wsb[tid] = (n < kNCLS) ? (bf16_t)Wk[k * kNCLS + n] : (bf16_t)0.0f;
  } else if (tid < 81920) {
    int t = tid - 16384; int n = t >> 8, k = t & 255;
    wsb[tid] = (bf16_t)Wv[k * kC + n];
  } else if (tid < 147456) {
    int t = tid - 81920; int n = t >> 8, k = t & 255;
    wsb[tid] = (bf16_t)Wres[k * kC + n];
  }
}

__global__ __launch_bounds__(256, 2) void semwin_main(
    const float* __restrict__ x,
    const float* __restrict__ bq, const float* __restrict__ bk,
    const float* __restrict__ bv, const float* __restrict__ bres,
    const float* __restrict__ gamma,
    const bf16_t* __restrict__ wsb,
    float* __restrict__ out0, float* __restrict__ out1)
{
  // LDS budget: 33792 + 10240 + 9216 + 9216 = 62464 B  -> 2 wg/CU
  __shared__ bf16_t xs[64][264];               // x window bf16, +8 pad
  __shared__ __align__(16) char qkf2[10240];   // Qs[64][40]+Ks[64][40], later F2c[64][72]
  __shared__ bf16_t Ps[64][72];                // softmax probs
  __shared__ bf16_t Vtc[64][72];               // V^T chunk: [ch_local][token]

  bf16_t (* const Qs)[40]  = (bf16_t(*)[40])(qkf2);
  bf16_t (* const Ks)[40]  = (bf16_t(*)[40])(qkf2 + 5120);
  bf16_t (* const F2c)[72] = (bf16_t(*)[72])(qkf2);

  const int tid  = threadIdx.x;
  const int wave = tid >> 6;
  const int lane = tid & 63;
  const int l15  = lane & 15;
  const int g    = lane >> 4;

  const int wid = blockIdx.x;
  const int b   = wid >> 10;
  const int wh  = (wid >> 5) & 31;
  const int ww  = wid & 31;
  const int pixbase = (b << 16) + (wh << 11) + (ww << 3);
  // pixel(t) = pixbase + (t>>3)*256 + (t&7)

  const f32x4 fzero = {0.f, 0.f, 0.f, 0.f};

  // ---- stage x window -> xs (bf16) ----
  {
    const int t  = tid >> 2;
    const int cb = (tid & 3) << 6;
    const float* src = x + (size_t)(pixbase + ((t >> 3) << 8) + (t & 7)) * kC + cb;
#pragma unroll
    for (int i = 0; i < 8; ++i) {
      f32x4 a = *(const f32x4*)(src + i * 8);
      f32x4 c = *(const f32x4*)(src + i * 8 + 4);
      bf16x8 v;
      v[0] = (bf16_t)a[0]; v[1] = (bf16_t)a[1]; v[2] = (bf16_t)a[2]; v[3] = (bf16_t)a[3];
      v[4] = (bf16_t)c[0]; v[5] = (bf16_t)c[1]; v[6] = (bf16_t)c[2]; v[7] = (bf16_t)c[3];
      *(bf16x8*)&xs[t][cb + i * 8] = v;
    }
  }
  __syncthreads();

  // ---- phase A: Q = xw@Wq + bq (waves 0,1); K = xw@Wk + bk (waves 2,3) ----
  {
    const bf16_t* wt   = wsb + ((wave < 2) ? WQT_OFF : WKT_OFF);
    const float*  bias = (wave < 2) ? bq : bk;
    const int mbase = (wave & 1) << 5;  // rows 0..31 or 32..63
    f32x4 acc[2][2];
#pragma unroll
    for (int mt = 0; mt < 2; ++mt)
#pragma unroll
      for (int nt = 0; nt < 2; ++nt) acc[mt][nt] = fzero;
#pragma unroll
    for (int k0 = 0; k0 < 256; k0 += 32) {
      bf16x8 a0 = *(const bf16x8*)&xs[mbase + l15][k0 + g * 8];
      bf16x8 a1 = *(const bf16x8*)&xs[mbase + 16 + l15][k0 + g * 8];
      bf16x8 b0 = *(const bf16x8*)(wt + l15 * 256 + k0 + g * 8);
      bf16x8 b1 = *(const bf16x8*)(wt + (16 + l15) * 256 + k0 + g * 8);
      acc[0][0] = MFMA16(a0, b0, acc[0][0]);
      acc[0][1] = MFMA16(a0, b1, acc[0][1]);
      acc[1][0] = MFMA16(a1, b0, acc[1][0]);
      acc[1][1] = MFMA16(a1, b1, acc[1][1]);
    }
    bf16_t (* const dst)[40] = (wave < 2) ? Qs : Ks;
    const bool isQ = (wave < 2);
#pragma unroll
    for (int nt = 0; nt < 2; ++nt) {
      const int coln = (nt << 4) + l15;
      const float bval = (coln < kNCLS) ? bias[coln] : 0.f;
#pragma unroll
      for (int mt = 0; mt < 2; ++mt) {
#pragma unroll
        for (int r = 0; r < 4; ++r) {
          const int row = mbase + (mt << 4) + (g << 2) + r;  // token
          const float v = acc[mt][nt][r] + bval;
          dst[row][coln] = (bf16_t)v;
          if (isQ && coln < kNCLS) {
            out0[(size_t)(pixbase + ((row >> 3) << 8) + (row & 7)) * kNCLS + coln] = v;
          }
        }
      }
    }
  }
  __syncthreads();

  // ---- phase S: S = Q K^T (64x64, K=32 padded), in-register softmax -> Ps ----
  {
    const int mbase = wave << 4;
    const bf16x8 aq = *(const bf16x8*)&Qs[mbase + l15][g * 8];
    f32x4 s[4];
#pragma unroll
    for (int nt = 0; nt < 4; ++nt) {
      bf16x8 bk8 = *(const bf16x8*)&Ks[(nt << 4) + l15][g * 8];
      s[nt] = MFMA16(aq, bk8, fzero);
    }
#pragma unroll
    for (int r = 0; r < 4; ++r) {
      float m = fmaxf(fmaxf(s[0][r], s[1][r]), fmaxf(s[2][r], s[3][r]));
#pragma unroll
      for (int off = 1; off < 16; off <<= 1) m = fmaxf(m, __shfl_xor(m, off));
      float e0 = __expf(s[0][r] - m), e1 = __expf(s[1][r] - m);
      float e2 = __expf(s[2][r] - m), e3 = __expf(s[3][r] - m);
      float sum = (e0 + e1) + (e2 + e3);
#pragma unroll
      for (int off = 1; off < 16; off <<= 1) sum += __shfl_xor(sum, off);
      const float inv = 1.0f / sum;
      const int row = mbase + (g << 2) + r;
      Ps[row][l15]      = (bf16_t)(e0 * inv);
      Ps[row][16 + l15] = (bf16_t)(e1 * inv);
      Ps[row][32 + l15] = (bf16_t)(e2 * inv);
      Ps[row][48 + l15] = (bf16_t)(e3 * inv);
    }
  }
  __syncthreads();

  // ---- chunked V / PV / residual-GEMM over 4 channel chunks of 64 ----
  f32x4 accD[4][4];
#pragma unroll
  for (int mt = 0; mt < 4; ++mt)
#pragma unroll
    for (int nt = 0; nt < 4; ++nt) accD[mt][nt] = fzero;

  for (int chunk = 0; chunk < 4; ++chunk) {
    // phase Bc: V[:, chunk*64 + wave*16 .. +16) -> Vtc[ch_local][token]
    {
      const bf16_t* wvt = wsb + WVT_OFF + (size_t)((chunk << 6) + (wave << 4)) * 256;
      f32x4 accV[4];
#pragma unroll
      for (int mt = 0; mt < 4; ++mt) accV[mt] = fzero;
#pragma unroll
      for (int k0 = 0; k0 < 256; k0 += 32) {
        bf16x8 bf = *(const bf16x8*)(wvt + l15 * 256 + k0 + g * 8);
#pragma unroll
        for (int mt = 0; mt < 4; ++mt) {
          bf16x8 af = *(const bf16x8*)&xs[(mt << 4) + l15][k0 + g * 8];
          accV[mt] = MFMA16(af, bf, accV[mt]);
        }
      }
      const float bvv = bv[(chunk << 6) + (wave << 4) + l15];
#pragma unroll
      for (int mt = 0; mt < 4; ++mt) {
        bf16x4 pk;
#pragma unroll
        for (int r = 0; r < 4; ++r) pk[r] = (bf16_t)(accV[mt][r] + bvv);
        *(bf16x4*)&Vtc[(wave << 4) + l15][(mt << 4) + (g << 2)] = pk;  // pack 4 tokens
      }
    }
    __syncthreads();

    // phase Cc: F2^T chunk = V^T_chunk @ P^T  -> F2c[token][ch_local]
    {
      f32x4 accC[4];
#pragma unroll
      for (int nt = 0; nt < 4; ++nt) accC[nt] = fzero;
#pragma unroll
      for (int k0 = 0; k0 < 64; k0 += 32) {
        bf16x8 av = *(const bf16x8*)&Vtc[(wave << 4) + l15][k0 + g * 8];
#pragma unroll
        for (int nt = 0; nt < 4; ++nt) {
          bf16x8 bp = *(const bf16x8*)&Ps[(nt << 4) + l15][k0 + g * 8];
          accC[nt] = MFMA16(av, bp, accC[nt]);
        }
      }
#pragma unroll
      for (int nt = 0; nt < 4; ++nt) {
        bf16x4 pk;
#pragma unroll
        for (int r = 0; r < 4; ++r) pk[r] = (bf16_t)accC[nt][r];
        *(bf16x4*)&F2c[(nt << 4) + l15][(wave << 4) + (g << 2)] = pk;  // pack 4 ch
      }
    }
    __syncthreads();

    // phase Dc: accD += WresT[wave rows][chunk cols] @ F2c
    {
      const bf16_t* wrt = wsb + WRT_OFF + (size_t)(wave << 6) * 256 + (chunk << 6);
#pragma unroll
      for (int k0 = 0; k0 < 64; k0 += 32) {
        bf16x8 bfr[4];
#pragma unroll
        for (int nt = 0; nt < 4; ++nt)
          bfr[nt] = *(const bf16x8*)&F2c[(nt << 4) + l15][k0 + g * 8];
#pragma unroll
        for (int mt = 0; mt < 4; ++mt) {
          bf16x8 af = *(const bf16x8*)(wrt + (size_t)((mt << 4) + l15) * 256 + k0 + g * 8);
#pragma unroll
          for (int nt = 0; nt < 4; ++nt) accD[mt][nt] = MFMA16(af, bfr[nt], accD[mt][nt]);
        }
      }
    }
    __syncthreads();
  }

  // ---- epilogue: out1 = gamma*(F3 + bres) + xw ----
  {
    const float gm = gamma[0];
#pragma unroll
    for (int mt = 0; mt < 4; ++mt) {
      const int c2 = (wave << 6) + (mt << 4) + (g << 2);
      const f32x4 br = *(const f32x4*)(bres + c2);
#pragma unroll
      for (int nt = 0; nt < 4; ++nt) {
        const int t = (nt << 4) + l15;
        const bf16x4 xv = *(const bf16x4*)&xs[t][c2];
        f32x4 o;
#pragma unroll
        for (int r = 0; r < 4; ++r)
          o[r] = gm * (accD[mt][nt][r] + br[r]) + (float)xv[r];
        *(f32x4*)(out1 + (size_t)(pixbase + ((t >> 3) << 8) + (t & 7)) * kC + c2) = o;
      }
    }
  }
}

extern "C" void kernel_launch(void* const* d_in, const int* in_sizes, int n_in,
                              void* d_out, int out_size, void* d_ws, size_t ws_size,
                              hipStream_t stream)
{
  const float* x     = (const float*)d_in[0];
  const float* Wq    = (const float*)d_in[1];
  const float* bq    = (const float*)d_in[2];
  const float* Wk    = (const float*)d_in[3];
  const float* bk    = (const float*)d_in[4];
  const float* Wv    = (const float*)d_in[5];
  const float* bv    = (const float*)d_in[6];
  const float* Wres  = (const float*)d_in[7];
  const float* bres  = (const float*)d_in[8];
  const float* gamma = (const float*)d_in[9];
  bf16_t* wsb = (bf16_t*)d_ws;   // needs 147456*2 = 294912 B
  float* out0 = (float*)d_out;                    // (8,256,256,18)
  float* out1 = out0 + (size_t)8 * 256 * 256 * 18; // (8,256,256,256)

  prep_weights_kernel<<<dim3(576), dim3(256), 0, stream>>>(Wq, Wk, Wv, Wres, wsb);
  semwin_main<<<dim3(8192), dim3(256), 0, stream>>>(x, bq, bk, bv, bres, gamma, wsb, out0, out1);
}

// Round 2
// 443.742 us; speedup vs baseline: 1.1491x; 1.1491x over previous
//
#include <hip/hip_runtime.h>
#include <hip/hip_bf16.h>

// SemWindowAttention: B=8, H=W=256, C=256, WS=8, NCLS=18
// windows = 8*32*32 = 8192, tokens/window = 64

typedef __bf16 bf16_t;
typedef __bf16 bf16x8 __attribute__((ext_vector_type(8)));
typedef __bf16 bf16x4 __attribute__((ext_vector_type(4)));
typedef float  f32x4  __attribute__((ext_vector_type(4)));

#define MFMA16(a, b, c) __builtin_amdgcn_mfma_f32_16x16x32_bf16((a), (b), (c), 0, 0, 0)

static constexpr int kC = 256, kNCLS = 18;
// ws bf16 layout (element offsets)
static constexpr int WQT_OFF = 0;        // WqT[32][256]  (n-major, zero-padded 18..31)
static constexpr int WKT_OFF = 8192;     // WkT[32][256]
static constexpr int WVT_OFF = 16384;    // WvT[256][256] (WvT[n][k] = Wv[k][n])
static constexpr int WRT_OFF = 81920;    // WresT[256][256]

__global__ __launch_bounds__(256) void prep_weights_kernel(
    const float* __restrict__ Wq, const float* __restrict__ Wk,
    const float* __restrict__ Wv, const float* __restrict__ Wres,
    bf16_t* __restrict__ wsb)
{
  int tid = blockIdx.x * 256 + threadIdx.x;
  if (tid < 8192) {
    int n = tid >> 8, k = tid & 255;
    wsb[tid] = (n < kNCLS) ? (bf16_t)Wq[k * kNCLS + n] : (bf16_t)0.0f;
  } else if (tid < 16384) {
    int t = tid - 8192; int n = t >> 8, k = t & 255;
    wsb[tid] = (n < kNCLS) ? (bf16_t)Wk[k * kNCLS + n] : (bf16_t)0.0f;
  } else if (tid < 81920) {
    int t = tid - 16384; int n = t >> 8, k = t & 255;
    wsb[tid] = (bf16_t)Wv[k * kC + n];
  } else if (tid < 147456) {
    int t = tid - 81920; int n = t >> 8, k = t & 255;
    wsb[tid] = (bf16_t)Wres[k * kC + n];
  }
}

__global__ __launch_bounds__(256, 3) void semwin_main(
    const float* __restrict__ x,
    const float* __restrict__ bq, const float* __restrict__ bk,
    const float* __restrict__ bv, const float* __restrict__ bres,
    const float* __restrict__ gamma,
    const bf16_t* __restrict__ wsb,
    float* __restrict__ out0, float* __restrict__ out1)
{
  // LDS budget: 33792 + 10240 + 9216 = 53248 B -> 3 wg/CU (163840/3 = 54613)
  __shared__ bf16_t xs[64][264];               // x window bf16, +8 pad
  __shared__ __align__(16) char buf1[10240];   // Qs[64][40]+Ks[64][40] -> Ps[64][72]
  __shared__ __align__(16) char buf2[9216];    // Vtc[64][72] -> F2c[64][72]

  bf16_t (* const Qs)[40]  = (bf16_t(*)[40])(buf1);
  bf16_t (* const Ks)[40]  = (bf16_t(*)[40])(buf1 + 5120);
  bf16_t (* const Ps)[72]  = (bf16_t(*)[72])(buf1);
  bf16_t (* const Vtc)[72] = (bf16_t(*)[72])(buf2);
  bf16_t (* const F2c)[72] = (bf16_t(*)[72])(buf2);

  const int tid  = threadIdx.x;
  const int wave = tid >> 6;
  const int lane = tid & 63;
  const int l15  = lane & 15;
  const int g    = lane >> 4;

  const int wid = blockIdx.x;
  const int b   = wid >> 10;
  const int wh  = (wid >> 5) & 31;
  const int ww  = wid & 31;
  const int pixbase = (b << 16) + (wh << 11) + (ww << 3);
  // pixel(t) = pixbase + (t>>3)*256 + (t&7)

  const f32x4 fzero = {0.f, 0.f, 0.f, 0.f};

  // ---- stage x window -> xs (bf16) ----
  // col = i*32 + q*8: per i, lanes 0..3 read 128B contiguous of row t (coalesced),
  // LDS write banks = 4*(row) + 4*q mod 32 -> <=2-way (free).
  {
    const int t = tid >> 2;
    const int q = tid & 3;
    const float* src = x + (size_t)(pixbase + ((t >> 3) << 8) + (t & 7)) * kC + q * 8;
#pragma unroll
    for (int i = 0; i < 8; ++i) {
      f32x4 a = *(const f32x4*)(src + i * 32);
      f32x4 c = *(const f32x4*)(src + i * 32 + 4);
      bf16x8 v;
      v[0] = (bf16_t)a[0]; v[1] = (bf16_t)a[1]; v[2] = (bf16_t)a[2]; v[3] = (bf16_t)a[3];
      v[4] = (bf16_t)c[0]; v[5] = (bf16_t)c[1]; v[6] = (bf16_t)c[2]; v[7] = (bf16_t)c[3];
      *(bf16x8*)&xs[t][i * 32 + q * 8] = v;
    }
  }
  __syncthreads();

  // ---- phase A: Q = xw@Wq + bq (waves 0,1); K = xw@Wk + bk (waves 2,3) ----
  {
    const bf16_t* wt   = wsb + ((wave < 2) ? WQT_OFF : WKT_OFF);
    const float*  bias = (wave < 2) ? bq : bk;
    const int mbase = (wave & 1) << 5;  // rows 0..31 or 32..63
    f32x4 acc[2][2];
#pragma unroll
    for (int mt = 0; mt < 2; ++mt)
#pragma unroll
      for (int nt = 0; nt < 2; ++nt) acc[mt][nt] = fzero;
#pragma unroll
    for (int k0 = 0; k0 < 256; k0 += 32) {
      bf16x8 a0 = *(const bf16x8*)&xs[mbase + l15][k0 + g * 8];
      bf16x8 a1 = *(const bf16x8*)&xs[mbase + 16 + l15][k0 + g * 8];
      bf16x8 b0 = *(const bf16x8*)(wt + l15 * 256 + k0 + g * 8);
      bf16x8 b1 = *(const bf16x8*)(wt + (16 + l15) * 256 + k0 + g * 8);
      acc[0][0] = MFMA16(a0, b0, acc[0][0]);
      acc[0][1] = MFMA16(a0, b1, acc[0][1]);
      acc[1][0] = MFMA16(a1, b0, acc[1][0]);
      acc[1][1] = MFMA16(a1, b1, acc[1][1]);
    }
    bf16_t (* const dst)[40] = (wave < 2) ? Qs : Ks;
    const bool isQ = (wave < 2);
#pragma unroll
    for (int nt = 0; nt < 2; ++nt) {
      const int coln = (nt << 4) + l15;
      const float bval = (coln < kNCLS) ? bias[coln] : 0.f;
#pragma unroll
      for (int mt = 0; mt < 2; ++mt) {
#pragma unroll
        for (int r = 0; r < 4; ++r) {
          const int row = mbase + (mt << 4) + (g << 2) + r;  // token
          const float v = acc[mt][nt][r] + bval;
          dst[row][coln] = (bf16_t)v;
          if (isQ && coln < kNCLS) {
            out0[(size_t)(pixbase + ((row >> 3) << 8) + (row & 7)) * kNCLS + coln] = v;
          }
        }
      }
    }
  }
  __syncthreads();

  // ---- phase S: S = Q K^T (64x64, K=32 padded), in-register softmax -> Ps ----
  // Reads of Qs/Ks complete before the mid-phase barrier; Ps then overwrites buf1.
  {
    const int mbase = wave << 4;
    const bf16x8 aq = *(const bf16x8*)&Qs[mbase + l15][g * 8];
    f32x4 s[4];
#pragma unroll
    for (int nt = 0; nt < 4; ++nt) {
      bf16x8 bk8 = *(const bf16x8*)&Ks[(nt << 4) + l15][g * 8];
      s[nt] = MFMA16(aq, bk8, fzero);
    }
    __syncthreads();  // all waves done reading Qs/Ks
#pragma unroll
    for (int r = 0; r < 4; ++r) {
      float m = fmaxf(fmaxf(s[0][r], s[1][r]), fmaxf(s[2][r], s[3][r]));
#pragma unroll
      for (int off = 1; off < 16; off <<= 1) m = fmaxf(m, __shfl_xor(m, off));
      float e0 = __expf(s[0][r] - m), e1 = __expf(s[1][r] - m);
      float e2 = __expf(s[2][r] - m), e3 = __expf(s[3][r] - m);
      float sum = (e0 + e1) + (e2 + e3);
#pragma unroll
      for (int off = 1; off < 16; off <<= 1) sum += __shfl_xor(sum, off);
      const float inv = 1.0f / sum;
      const int row = mbase + (g << 2) + r;
      Ps[row][l15]      = (bf16_t)(e0 * inv);
      Ps[row][16 + l15] = (bf16_t)(e1 * inv);
      Ps[row][32 + l15] = (bf16_t)(e2 * inv);
      Ps[row][48 + l15] = (bf16_t)(e3 * inv);
    }
  }
  __syncthreads();

  // ---- chunked V / PV / residual-GEMM over 4 channel chunks of 64 ----
  f32x4 accD[4][4];
#pragma unroll
  for (int mt = 0; mt < 4; ++mt)
#pragma unroll
    for (int nt = 0; nt < 4; ++nt) accD[mt][nt] = fzero;

  for (int chunk = 0; chunk < 4; ++chunk) {
    // phase Bc: V[:, chunk*64 + wave*16 .. +16) -> Vtc[ch_local][token]
    {
      const bf16_t* wvt = wsb + WVT_OFF + (size_t)((chunk << 6) + (wave << 4)) * 256;
      f32x4 accV[4];
#pragma unroll
      for (int mt = 0; mt < 4; ++mt) accV[mt] = fzero;
#pragma unroll
      for (int k0 = 0; k0 < 256; k0 += 32) {
        bf16x8 bf = *(const bf16x8*)(wvt + l15 * 256 + k0 + g * 8);
#pragma unroll
        for (int mt = 0; mt < 4; ++mt) {
          bf16x8 af = *(const bf16x8*)&xs[(mt << 4) + l15][k0 + g * 8];
          accV[mt] = MFMA16(af, bf, accV[mt]);
        }
      }
      const float bvv = bv[(chunk << 6) + (wave << 4) + l15];
#pragma unroll
      for (int mt = 0; mt < 4; ++mt) {
        bf16x4 pk;
#pragma unroll
        for (int r = 0; r < 4; ++r) pk[r] = (bf16_t)(accV[mt][r] + bvv);
        *(bf16x4*)&Vtc[(wave << 4) + l15][(mt << 4) + (g << 2)] = pk;  // pack 4 tokens
      }
    }
    __syncthreads();

    // phase Cc: F2^T chunk = V^T_chunk @ P^T (into regs), then overwrite buf2
    {
      f32x4 accC[4];
#pragma unroll
      for (int nt = 0; nt < 4; ++nt) accC[nt] = fzero;
#pragma unroll
      for (int k0 = 0; k0 < 64; k0 += 32) {
        bf16x8 av = *(const bf16x8*)&Vtc[(wave << 4) + l15][k0 + g * 8];
#pragma unroll
        for (int nt = 0; nt < 4; ++nt) {
          bf16x8 bp = *(const bf16x8*)&Ps[(nt << 4) + l15][k0 + g * 8];
          accC[nt] = MFMA16(av, bp, accC[nt]);
        }
      }
      __syncthreads();  // all waves done reading Vtc
#pragma unroll
      for (int nt = 0; nt < 4; ++nt) {
        bf16x4 pk;
#pragma unroll
        for (int r = 0; r < 4; ++r) pk[r] = (bf16_t)accC[nt][r];
        *(bf16x4*)&F2c[(nt << 4) + l15][(wave << 4) + (g << 2)] = pk;  // pack 4 ch
      }
    }
    __syncthreads();

    // phase Dc: accD += WresT[wave rows][chunk cols] @ F2c
    {
      const bf16_t* wrt = wsb + WRT_OFF + (size_t)(wave << 6) * 256 + (chunk << 6);
#pragma unroll
      for (int k0 = 0; k0 < 64; k0 += 32) {
        bf16x8 bfr[4];
#pragma unroll
        for (int nt = 0; nt < 4; ++nt)
          bfr[nt] = *(const bf16x8*)&F2c[(nt << 4) + l15][k0 + g * 8];
#pragma unroll
        for (int mt = 0; mt < 4; ++mt) {
          bf16x8 af = *(const bf16x8*)(wrt + (size_t)((mt << 4) + l15) * 256 + k0 + g * 8);
#pragma unroll
          for (int nt = 0; nt < 4; ++nt) accD[mt][nt] = MFMA16(af, bfr[nt], accD[mt][nt]);
        }
      }
    }
    __syncthreads();
  }

  // ---- epilogue: out1 = gamma*(F3 + bres) + xw ----
  {
    const float gm = gamma[0];
#pragma unroll
    for (int mt = 0; mt < 4; ++mt) {
      const int c2 = (wave << 6) + (mt << 4) + (g << 2);
      const f32x4 br = *(const f32x4*)(bres + c2);
#pragma unroll
      for (int nt = 0; nt < 4; ++nt) {
        const int t = (nt << 4) + l15;
        const bf16x4 xv = *(const bf16x4*)&xs[t][c2];
        f32x4 o;
#pragma unroll
        for (int r = 0; r < 4; ++r)
          o[r] = gm * (accD[mt][nt][r] + br[r]) + (float)xv[r];
        *(f32x4*)(out1 + (size_t)(pixbase + ((t >> 3) << 8) + (t & 7)) * kC + c2) = o;
      }
    }
  }
}

extern "C" void kernel_launch(void* const* d_in, const int* in_sizes, int n_in,
                              void* d_out, int out_size, void* d_ws, size_t ws_size,
                              hipStream_t stream)
{
  const float* x     = (const float*)d_in[0];
  const float* Wq    = (const float*)d_in[1];
  const float* bq    = (const float*)d_in[2];
  const float* Wk    = (const float*)d_in[3];
  const float* bk    = (const float*)d_in[4];
  const float* Wv    = (const float*)d_in[5];
  const float* bv    = (const float*)d_in[6];
  const float* Wres  = (const float*)d_in[7];
  const float* bres  = (const float*)d_in[8];
  const float* gamma = (const float*)d_in[9];
  bf16_t* wsb = (bf16_t*)d_ws;   // needs 147456*2 = 294912 B
  float* out0 = (float*)d_out;                     // (8,256,256,18)
  float* out1 = out0 + (size_t)8 * 256 * 256 * 18; // (8,256,256,256)

  prep_weights_kernel<<<dim3(576), dim3(256), 0, stream>>>(Wq, Wk, Wv, Wres, wsb);
  semwin_main<<<dim3(8192), dim3(256), 0, stream>>>(x, bq, bk, bv, bres, gamma, wsb, out0, out1);
}

// Round 3
// 324.222 us; speedup vs baseline: 1.5727x; 1.3686x over previous
//
#include <hip/hip_runtime.h>
#include <hip/hip_bf16.h>

// SemWindowAttention: B=8, H=W=256, C=256, WS=8, NCLS=18
// windows = 8*32*32 = 8192, tokens/window = 64
//
// Algebraic fusion: softmax rows sum to 1 =>
//   out1 = gamma*( P @ (x @ Wf) + bf ) + x,  Wf = Wv@Wres, bf = bv@Wres + bres
// This removes one full 64x256x256 GEMM per window vs the naive chain.

typedef __bf16 bf16_t;
typedef __bf16 bf16x8 __attribute__((ext_vector_type(8)));
typedef __bf16 bf16x4 __attribute__((ext_vector_type(4)));
typedef float  f32x4  __attribute__((ext_vector_type(4)));

#define MFMA16(a, b, c) __builtin_amdgcn_mfma_f32_16x16x32_bf16((a), (b), (c), 0, 0, 0)

static constexpr int kC = 256, kNCLS = 18;
// ws bf16 layout (element offsets)
static constexpr int WQT_OFF = 0;        // WqT[32][256]  (n-major, zero-padded 18..31)
static constexpr int WKT_OFF = 8192;     // WkT[32][256]
static constexpr int WFT_OFF = 16384;    // WfT[256][256], WfT[n][k] = Wf[k][n]
static constexpr int BF_BYTE_OFF = 81920 * 2;  // float bf[256] after bf16 section

__global__ __launch_bounds__(256) void prep_kernel(
    const float* __restrict__ Wq, const float* __restrict__ Wk,
    const float* __restrict__ Wv, const float* __restrict__ bv,
    const float* __restrict__ Wres, const float* __restrict__ bres,
    bf16_t* __restrict__ wsb, float* __restrict__ bff)
{
  const int blk = blockIdx.x, t = threadIdx.x;
  if (blk < 256) {
    // WfT[n][k] = sum_j Wv[k][j] * Wres[j][n], one block per n, thread = k
    __shared__ float wcol[256];
    const int n = blk;
    wcol[t] = Wres[t * kC + n];
    __syncthreads();
    float acc = 0.f;
    const float* wvrow = Wv + (size_t)t * kC;
#pragma unroll 4
    for (int j = 0; j < 256; j += 4) {
      f32x4 a = *(const f32x4*)(wvrow + j);
      acc += a[0] * wcol[j] + a[1] * wcol[j + 1] + a[2] * wcol[j + 2] + a[3] * wcol[j + 3];
    }
    wsb[WFT_OFF + n * kC + t] = (bf16_t)acc;
  } else if (blk == 256) {
    // bf[n] = sum_j bv[j]*Wres[j][n] + bres[n]
    float acc = bres[t];
    for (int j = 0; j < 256; ++j) acc += bv[j] * Wres[j * kC + t];
    bff[t] = acc;
  } else {
    int tid = (blk - 257) * 256 + t;  // 0..16383
    if (tid < 8192) {
      int n = tid >> 8, k = tid & 255;
      wsb[WQT_OFF + tid] = (n < kNCLS) ? (bf16_t)Wq[k * kNCLS + n] : (bf16_t)0.0f;
    } else {
      int u = tid - 8192;
      int n = u >> 8, k = u & 255;
      wsb[WKT_OFF + u] = (n < kNCLS) ? (bf16_t)Wk[k * kNCLS + n] : (bf16_t)0.0f;
    }
  }
}

__global__ __launch_bounds__(256, 3) void semwin_main(
    const float* __restrict__ x,
    const float* __restrict__ bq, const float* __restrict__ bk,
    const float* __restrict__ gamma,
    const bf16_t* __restrict__ wsb, const float* __restrict__ bff,
    float* __restrict__ out0, float* __restrict__ out1)
{
  // LDS: 33792 + 10240 + 9216 = 53248 B -> 3 wg/CU (163840/3 = 54613)
  __shared__ bf16_t xs[64][264];               // x window bf16, +8 pad
  __shared__ __align__(16) char buf1[10240];   // Qs[64][40]+Ks[64][40] -> Ps[64][72]
  __shared__ __align__(16) char buf2[9216];    // Utc[64][72]  (U^T chunk: [ch][token])

  bf16_t (* const Qs)[40]  = (bf16_t(*)[40])(buf1);
  bf16_t (* const Ks)[40]  = (bf16_t(*)[40])(buf1 + 5120);
  bf16_t (* const Ps)[72]  = (bf16_t(*)[72])(buf1);
  bf16_t (* const Utc)[72] = (bf16_t(*)[72])(buf2);

  const int tid  = threadIdx.x;
  const int wave = tid >> 6;
  const int lane = tid & 63;
  const int l15  = lane & 15;
  const int g    = lane >> 4;

  const int wid = blockIdx.x;
  const int b   = wid >> 10;
  const int wh  = (wid >> 5) & 31;
  const int ww  = wid & 31;
  const int pixbase = (b << 16) + (wh << 11) + (ww << 3);
  // pixel(t) = pixbase + (t>>3)*256 + (t&7)

  const f32x4 fzero = {0.f, 0.f, 0.f, 0.f};
  const float gm = gamma[0];

  // ---- stage x window -> xs (bf16) ----
  {
    const int t = tid >> 2;
    const int q = tid & 3;
    const float* src = x + (size_t)(pixbase + ((t >> 3) << 8) + (t & 7)) * kC + q * 8;
#pragma unroll
    for (int i = 0; i < 8; ++i) {
      f32x4 a = *(const f32x4*)(src + i * 32);
      f32x4 c = *(const f32x4*)(src + i * 32 + 4);
      bf16x8 v;
      v[0] = (bf16_t)a[0]; v[1] = (bf16_t)a[1]; v[2] = (bf16_t)a[2]; v[3] = (bf16_t)a[3];
      v[4] = (bf16_t)c[0]; v[5] = (bf16_t)c[1]; v[6] = (bf16_t)c[2]; v[7] = (bf16_t)c[3];
      *(bf16x8*)&xs[t][i * 32 + q * 8] = v;
    }
  }
  __syncthreads();

  // ---- phase A: Q = xw@Wq + bq (waves 0,1); K = xw@Wk + bk (waves 2,3) ----
  {
    const bf16_t* wt   = wsb + ((wave < 2) ? WQT_OFF : WKT_OFF);
    const float*  bias = (wave < 2) ? bq : bk;
    const int mbase = (wave & 1) << 5;  // rows 0..31 or 32..63
    f32x4 acc[2][2];
#pragma unroll
    for (int mt = 0; mt < 2; ++mt)
#pragma unroll
      for (int nt = 0; nt < 2; ++nt) acc[mt][nt] = fzero;
#pragma unroll
    for (int k0 = 0; k0 < 256; k0 += 32) {
      bf16x8 a0 = *(const bf16x8*)&xs[mbase + l15][k0 + g * 8];
      bf16x8 a1 = *(const bf16x8*)&xs[mbase + 16 + l15][k0 + g * 8];
      bf16x8 b0 = *(const bf16x8*)(wt + l15 * 256 + k0 + g * 8);
      bf16x8 b1 = *(const bf16x8*)(wt + (16 + l15) * 256 + k0 + g * 8);
      acc[0][0] = MFMA16(a0, b0, acc[0][0]);
      acc[0][1] = MFMA16(a0, b1, acc[0][1]);
      acc[1][0] = MFMA16(a1, b0, acc[1][0]);
      acc[1][1] = MFMA16(a1, b1, acc[1][1]);
    }
    bf16_t (* const dst)[40] = (wave < 2) ? Qs : Ks;
    const bool isQ = (wave < 2);
#pragma unroll
    for (int nt = 0; nt < 2; ++nt) {
      const int coln = (nt << 4) + l15;
      const float bval = (coln < kNCLS) ? bias[coln] : 0.f;
#pragma unroll
      for (int mt = 0; mt < 2; ++mt) {
#pragma unroll
        for (int r = 0; r < 4; ++r) {
          const int row = mbase + (mt << 4) + (g << 2) + r;  // token
          const float v = acc[mt][nt][r] + bval;
          dst[row][coln] = (bf16_t)v;
          if (isQ && coln < kNCLS) {
            out0[(size_t)(pixbase + ((row >> 3) << 8) + (row & 7)) * kNCLS + coln] = v;
          }
        }
      }
    }
  }
  __syncthreads();

  // ---- phase S: S = Q K^T (64x64, K=32 padded), in-register softmax -> Ps ----
  {
    const int mbase = wave << 4;
    const bf16x8 aq = *(const bf16x8*)&Qs[mbase + l15][g * 8];
    f32x4 s[4];
#pragma unroll
    for (int nt = 0; nt < 4; ++nt) {
      bf16x8 bk8 = *(const bf16x8*)&Ks[(nt << 4) + l15][g * 8];
      s[nt] = MFMA16(aq, bk8, fzero);
    }
    __syncthreads();  // all waves done reading Qs/Ks (Ps aliases them)
#pragma unroll
    for (int r = 0; r < 4; ++r) {
      float m = fmaxf(fmaxf(s[0][r], s[1][r]), fmaxf(s[2][r], s[3][r]));
#pragma unroll
      for (int off = 1; off < 16; off <<= 1) m = fmaxf(m, __shfl_xor(m, off));
      float e0 = __expf(s[0][r] - m), e1 = __expf(s[1][r] - m);
      float e2 = __expf(s[2][r] - m), e3 = __expf(s[3][r] - m);
      float sum = (e0 + e1) + (e2 + e3);
#pragma unroll
      for (int off = 1; off < 16; off <<= 1) sum += __shfl_xor(sum, off);
      const float inv = 1.0f / sum;
      const int row = mbase + (g << 2) + r;
      Ps[row][l15]      = (bf16_t)(e0 * inv);
      Ps[row][16 + l15] = (bf16_t)(e1 * inv);
      Ps[row][32 + l15] = (bf16_t)(e2 * inv);
      Ps[row][48 + l15] = (bf16_t)(e3 * inv);
    }
  }
  __syncthreads();

  // ---- hoist P fragments to registers (reused by all 4 chunks) ----
  bf16x8 bp[4][2];
#pragma unroll
  for (int nt = 0; nt < 4; ++nt) {
    bp[nt][0] = *(const bf16x8*)&Ps[(nt << 4) + l15][g * 8];
    bp[nt][1] = *(const bf16x8*)&Ps[(nt << 4) + l15][32 + g * 8];
  }

  // ---- chunk loop: U chunk (x@Wf) -> Utc; out1 chunk = gamma*(U^T@P^T)^T+bf+x ----
  for (int chunk = 0; chunk < 4; ++chunk) {
    // phase Bc: U[:, chunk*64 + wave*16 .. +16) -> Utc[ch_local][token]
    {
      const bf16_t* wft = wsb + WFT_OFF + (size_t)((chunk << 6) + (wave << 4)) * 256;
      f32x4 accV[4];
#pragma unroll
      for (int mt = 0; mt < 4; ++mt) accV[mt] = fzero;
#pragma unroll
      for (int k0 = 0; k0 < 256; k0 += 32) {
        bf16x8 bf = *(const bf16x8*)(wft + l15 * 256 + k0 + g * 8);
#pragma unroll
        for (int mt = 0; mt < 4; ++mt) {
          bf16x8 af = *(const bf16x8*)&xs[(mt << 4) + l15][k0 + g * 8];
          accV[mt] = MFMA16(af, bf, accV[mt]);
        }
      }
#pragma unroll
      for (int mt = 0; mt < 4; ++mt) {
        bf16x4 pk;
#pragma unroll
        for (int r = 0; r < 4; ++r) pk[r] = (bf16_t)accV[mt][r];
        *(bf16x4*)&Utc[(wave << 4) + l15][(mt << 4) + (g << 2)] = pk;  // pack 4 tokens
      }
    }
    __syncthreads();

    // phase Cc: out^T chunk = U^T_chunk @ P^T, fused epilogue, direct store
    {
      const bf16x8 av0 = *(const bf16x8*)&Utc[(wave << 4) + l15][g * 8];
      const bf16x8 av1 = *(const bf16x8*)&Utc[(wave << 4) + l15][32 + g * 8];
      const int c2 = (chunk << 6) + (wave << 4) + (g << 2);
      const f32x4 bfv = *(const f32x4*)(bff + c2);
#pragma unroll
      for (int nt = 0; nt < 4; ++nt) {
        f32x4 accC = MFMA16(av0, bp[nt][0], fzero);
        accC = MFMA16(av1, bp[nt][1], accC);
        const int t = (nt << 4) + l15;
        const bf16x4 xv = *(const bf16x4*)&xs[t][c2];
        f32x4 o;
#pragma unroll
        for (int r = 0; r < 4; ++r)
          o[r] = gm * (accC[r] + bfv[r]) + (float)xv[r];
        *(f32x4*)(out1 + (size_t)(pixbase + ((t >> 3) << 8) + (t & 7)) * kC + c2) = o;
      }
    }
    if (chunk < 3) __syncthreads();  // protect Utc before next Bc overwrites it
  }
}

extern "C" void kernel_launch(void* const* d_in, const int* in_sizes, int n_in,
                              void* d_out, int out_size, void* d_ws, size_t ws_size,
                              hipStream_t stream)
{
  const float* x     = (const float*)d_in[0];
  const float* Wq    = (const float*)d_in[1];
  const float* bq    = (const float*)d_in[2];
  const float* Wk    = (const float*)d_in[3];
  const float* bk    = (const float*)d_in[4];
  const float* Wv    = (const float*)d_in[5];
  const float* bv    = (const float*)d_in[6];
  const float* Wres  = (const float*)d_in[7];
  const float* bres  = (const float*)d_in[8];
  const float* gamma = (const float*)d_in[9];
  bf16_t* wsb = (bf16_t*)d_ws;                         // 81920 bf16 = 163840 B
  float*  bff = (float*)((char*)d_ws + BF_BYTE_OFF);   // + 1024 B
  float* out0 = (float*)d_out;                         // (8,256,256,18)
  float* out1 = out0 + (size_t)8 * 256 * 256 * 18;     // (8,256,256,256)

  prep_kernel<<<dim3(321), dim3(256), 0, stream>>>(Wq, Wk, Wv, bv, Wres, bres, wsb, bff);
  semwin_main<<<dim3(8192), dim3(256), 0, stream>>>(x, bq, bk, gamma, wsb, bff, out0, out1);
}

// Round 4
// 315.819 us; speedup vs baseline: 1.6145x; 1.0266x over previous
//
#include <hip/hip_runtime.h>
#include <hip/hip_bf16.h>

// SemWindowAttention: B=8, H=W=256, C=256, WS=8, NCLS=18
// windows = 8*32*32 = 8192, tokens/window = 64
//
// Algebraic fusion: softmax rows sum to 1 =>
//   out1 = gamma*( P @ (x @ Wf) + bf ) + x,  Wf = Wv@Wres, bf = bv@Wres + bres
//
// This round: lgkm-only barriers (global stores never drain at barriers) +
// LDS cut to exactly 40960 B (XOR-swizzled xs, single aliased 8KB side buffer)
// -> 4 wg/CU.

typedef __bf16 bf16_t;
typedef __bf16 bf16x8 __attribute__((ext_vector_type(8)));
typedef __bf16 bf16x4 __attribute__((ext_vector_type(4)));
typedef float  f32x4  __attribute__((ext_vector_type(4)));

#define MFMA16(a, b, c) __builtin_amdgcn_mfma_f32_16x16x32_bf16((a), (b), (c), 0, 0, 0)
// All inter-phase deps are through LDS; let global stores fly across barriers.
#define BAR() do { asm volatile("s_waitcnt lgkmcnt(0)" ::: "memory"); \
                   __builtin_amdgcn_s_barrier(); } while (0)

static constexpr int kC = 256, kNCLS = 18;
// ws bf16 layout (element offsets)
static constexpr int WQT_OFF = 0;        // WqT[32][256]  (n-major, zero-padded 18..31)
static constexpr int WKT_OFF = 8192;     // WkT[32][256]
static constexpr int WFT_OFF = 16384;    // WfT[256][256], WfT[n][k] = Wf[k][n]
static constexpr int BF_BYTE_OFF = 81920 * 2;  // float bf[256] after bf16 section

// XOR swizzle: byte ^= (row&7)<<4  <=>  elem ^= (row&7)<<3 (bf16). Bijective per
// row; all fragment (16B) / x4 (8B) accesses keep low bits intact.
__device__ __forceinline__ int xs_i(int r, int c) { return (r << 8) + (c ^ ((r & 7) << 3)); }
__device__ __forceinline__ int sb_i(int r, int c) { return (r << 6) + (c ^ ((r & 7) << 3)); }

__global__ __launch_bounds__(256) void prep_kernel(
    const float* __restrict__ Wq, const float* __restrict__ Wk,
    const float* __restrict__ Wv, const float* __restrict__ bv,
    const float* __restrict__ Wres, const float* __restrict__ bres,
    bf16_t* __restrict__ wsb, float* __restrict__ bff)
{
  const int blk = blockIdx.x, t = threadIdx.x;
  if (blk < 256) {
    // WfT[n][k] = sum_j Wv[k][j] * Wres[j][n], one block per n, thread = k
    __shared__ float wcol[256];
    const int n = blk;
    wcol[t] = Wres[t * kC + n];
    __syncthreads();
    float acc = 0.f;
    const float* wvrow = Wv + (size_t)t * kC;
#pragma unroll 4
    for (int j = 0; j < 256; j += 4) {
      f32x4 a = *(const f32x4*)(wvrow + j);
      acc += a[0] * wcol[j] + a[1] * wcol[j + 1] + a[2] * wcol[j + 2] + a[3] * wcol[j + 3];
    }
    wsb[WFT_OFF + n * kC + t] = (bf16_t)acc;
  } else if (blk == 256) {
    // bf[n] = sum_j bv[j]*Wres[j][n] + bres[n]
    float acc = bres[t];
    for (int j = 0; j < 256; ++j) acc += bv[j] * Wres[j * kC + t];
    bff[t] = acc;
  } else {
    int tid = (blk - 257) * 256 + t;  // 0..16383
    if (tid < 8192) {
      int n = tid >> 8, k = tid & 255;
      wsb[WQT_OFF + tid] = (n < kNCLS) ? (bf16_t)Wq[k * kNCLS + n] : (bf16_t)0.0f;
    } else {
      int u = tid - 8192;
      int n = u >> 8, k = u & 255;
      wsb[WKT_OFF + u] = (n < kNCLS) ? (bf16_t)Wk[k * kNCLS + n] : (bf16_t)0.0f;
    }
  }
}

__global__ __launch_bounds__(256, 4) void semwin_main(
    const float* __restrict__ x,
    const float* __restrict__ bq, const float* __restrict__ bk,
    const float* __restrict__ gamma,
    const bf16_t* __restrict__ wsb, const float* __restrict__ bff,
    float* __restrict__ out0, float* __restrict__ out1)
{
  // LDS: 32768 + 8192 = 40960 B exactly -> 4 wg/CU (163840/4)
  __shared__ bf16_t xsf[64 * 256];  // x window bf16, XOR-swizzled rows
  __shared__ bf16_t sbf[64 * 64];   // QK[64][0:32|32:64] -> Ps[64][64] -> Utc[64][64]

  const int tid  = threadIdx.x;
  const int wave = tid >> 6;
  const int lane = tid & 63;
  const int l15  = lane & 15;
  const int g    = lane >> 4;

  const int wid = blockIdx.x;
  const int b   = wid >> 10;
  const int wh  = (wid >> 5) & 31;
  const int ww  = wid & 31;
  const int pixbase = (b << 16) + (wh << 11) + (ww << 3);
  // pixel(t) = pixbase + (t>>3)*256 + (t&7)

  const f32x4 fzero = {0.f, 0.f, 0.f, 0.f};
  const float gm = gamma[0];

  // ---- stage x window -> xs (bf16, swizzled) ----
  {
    const int t = tid >> 2;
    const int q = tid & 3;
    const float* src = x + (size_t)(pixbase + ((t >> 3) << 8) + (t & 7)) * kC + q * 8;
#pragma unroll
    for (int i = 0; i < 8; ++i) {
      f32x4 a = *(const f32x4*)(src + i * 32);
      f32x4 c = *(const f32x4*)(src + i * 32 + 4);
      bf16x8 v;
      v[0] = (bf16_t)a[0]; v[1] = (bf16_t)a[1]; v[2] = (bf16_t)a[2]; v[3] = (bf16_t)a[3];
      v[4] = (bf16_t)c[0]; v[5] = (bf16_t)c[1]; v[6] = (bf16_t)c[2]; v[7] = (bf16_t)c[3];
      *(bf16x8*)&xsf[xs_i(t, i * 32 + q * 8)] = v;
    }
  }
  BAR();

  // ---- phase A: Q = xw@Wq + bq (waves 0,1); K = xw@Wk + bk (waves 2,3) ----
  // QK buffer: rows = tokens, cols 0..31 = Q (padded), cols 32..63 = K.
  {
    const bf16_t* wt   = wsb + ((wave < 2) ? WQT_OFF : WKT_OFF);
    const float*  bias = (wave < 2) ? bq : bk;
    const int mbase = (wave & 1) << 5;  // rows 0..31 or 32..63
    const int cofs  = (wave < 2) ? 0 : 32;
    f32x4 acc[2][2];
#pragma unroll
    for (int mt = 0; mt < 2; ++mt)
#pragma unroll
      for (int nt = 0; nt < 2; ++nt) acc[mt][nt] = fzero;
#pragma unroll
    for (int k0 = 0; k0 < 256; k0 += 32) {
      bf16x8 a0 = *(const bf16x8*)&xsf[xs_i(mbase + l15, k0 + g * 8)];
      bf16x8 a1 = *(const bf16x8*)&xsf[xs_i(mbase + 16 + l15, k0 + g * 8)];
      bf16x8 b0 = *(const bf16x8*)(wt + l15 * 256 + k0 + g * 8);
      bf16x8 b1 = *(const bf16x8*)(wt + (16 + l15) * 256 + k0 + g * 8);
      acc[0][0] = MFMA16(a0, b0, acc[0][0]);
      acc[0][1] = MFMA16(a0, b1, acc[0][1]);
      acc[1][0] = MFMA16(a1, b0, acc[1][0]);
      acc[1][1] = MFMA16(a1, b1, acc[1][1]);
    }
    const bool isQ = (wave < 2);
#pragma unroll
    for (int nt = 0; nt < 2; ++nt) {
      const int coln = (nt << 4) + l15;
      const float bval = (coln < kNCLS) ? bias[coln] : 0.f;
#pragma unroll
      for (int mt = 0; mt < 2; ++mt) {
#pragma unroll
        for (int r = 0; r < 4; ++r) {
          const int row = mbase + (mt << 4) + (g << 2) + r;  // token
          const float v = acc[mt][nt][r] + bval;
          sbf[sb_i(row, cofs + coln)] = (bf16_t)v;
          if (isQ && coln < kNCLS) {
            out0[(size_t)(pixbase + ((row >> 3) << 8) + (row & 7)) * kNCLS + coln] = v;
          }
        }
      }
    }
  }
  BAR();

  // ---- phase S: S = Q K^T (64x64, K=32 padded), in-register softmax -> Ps ----
  {
    const int mbase = wave << 4;
    const bf16x8 aq = *(const bf16x8*)&sbf[sb_i(mbase + l15, g * 8)];
    f32x4 s[4];
#pragma unroll
    for (int nt = 0; nt < 4; ++nt) {
      bf16x8 bk8 = *(const bf16x8*)&sbf[sb_i((nt << 4) + l15, 32 + g * 8)];
      s[nt] = MFMA16(aq, bk8, fzero);
    }
    BAR();  // all waves done reading Q/K (Ps aliases them)
#pragma unroll
    for (int r = 0; r < 4; ++r) {
      float m = fmaxf(fmaxf(s[0][r], s[1][r]), fmaxf(s[2][r], s[3][r]));
#pragma unroll
      for (int off = 1; off < 16; off <<= 1) m = fmaxf(m, __shfl_xor(m, off));
      float e0 = __expf(s[0][r] - m), e1 = __expf(s[1][r] - m);
      float e2 = __expf(s[2][r] - m), e3 = __expf(s[3][r] - m);
      float sum = (e0 + e1) + (e2 + e3);
#pragma unroll
      for (int off = 1; off < 16; off <<= 1) sum += __shfl_xor(sum, off);
      const float inv = 1.0f / sum;
      const int row = mbase + (g << 2) + r;
      sbf[sb_i(row, l15)]      = (bf16_t)(e0 * inv);
      sbf[sb_i(row, 16 + l15)] = (bf16_t)(e1 * inv);
      sbf[sb_i(row, 32 + l15)] = (bf16_t)(e2 * inv);
      sbf[sb_i(row, 48 + l15)] = (bf16_t)(e3 * inv);
    }
  }
  BAR();

  // ---- hoist P fragments to registers (reused by all 4 chunks) ----
  bf16x8 bp[4][2];
#pragma unroll
  for (int nt = 0; nt < 4; ++nt) {
    bp[nt][0] = *(const bf16x8*)&sbf[sb_i((nt << 4) + l15, g * 8)];
    bp[nt][1] = *(const bf16x8*)&sbf[sb_i((nt << 4) + l15, 32 + g * 8)];
  }
  BAR();  // Ps reads done before Utc overwrites the buffer

  // ---- chunk loop: U chunk (x@Wf) -> Utc; out1 chunk = gamma*(U^T@P^T)^T+bf+x ----
  for (int chunk = 0; chunk < 4; ++chunk) {
    // phase Bc: U[:, chunk*64 + wave*16 .. +16) -> Utc[ch_local][token]
    {
      const bf16_t* wft = wsb + WFT_OFF + (size_t)((chunk << 6) + (wave << 4)) * 256;
      f32x4 accV[4];
#pragma unroll
      for (int mt = 0; mt < 4; ++mt) accV[mt] = fzero;
#pragma unroll
      for (int k0 = 0; k0 < 256; k0 += 32) {
        bf16x8 bf = *(const bf16x8*)(wft + l15 * 256 + k0 + g * 8);
#pragma unroll
        for (int mt = 0; mt < 4; ++mt) {
          bf16x8 af = *(const bf16x8*)&xsf[xs_i((mt << 4) + l15, k0 + g * 8)];
          accV[mt] = MFMA16(af, bf, accV[mt]);
        }
      }
#pragma unroll
      for (int mt = 0; mt < 4; ++mt) {
        bf16x4 pk;
#pragma unroll
        for (int r = 0; r < 4; ++r) pk[r] = (bf16_t)accV[mt][r];
        // Utc[ch 0..63][token], ch = wave*16+l15, tok = mt*16 + g*4
        *(bf16x4*)&sbf[sb_i((wave << 4) + l15, (mt << 4) + (g << 2))] = pk;
      }
    }
    BAR();

    // phase Cc: out^T chunk = U^T_chunk @ P^T, fused epilogue, direct store
    {
      const bf16x8 av0 = *(const bf16x8*)&sbf[sb_i((wave << 4) + l15, g * 8)];
      const bf16x8 av1 = *(const bf16x8*)&sbf[sb_i((wave << 4) + l15, 32 + g * 8)];
      const int c2 = (chunk << 6) + (wave << 4) + (g << 2);
      const f32x4 bfv = *(const f32x4*)(bff + c2);
#pragma unroll
      for (int nt = 0; nt < 4; ++nt) {
        f32x4 accC = MFMA16(av0, bp[nt][0], fzero);
        accC = MFMA16(av1, bp[nt][1], accC);
        const int t = (nt << 4) + l15;
        const bf16x4 xv = *(const bf16x4*)&xsf[xs_i(t, c2)];
        f32x4 o;
#pragma unroll
        for (int r = 0; r < 4; ++r)
          o[r] = gm * (accC[r] + bfv[r]) + (float)xv[r];
        *(f32x4*)(out1 + (size_t)(pixbase + ((t >> 3) << 8) + (t & 7)) * kC + c2) = o;
      }
    }
    if (chunk < 3) BAR();  // protect Utc reads before next Bc overwrites
  }
}

extern "C" void kernel_launch(void* const* d_in, const int* in_sizes, int n_in,
                              void* d_out, int out_size, void* d_ws, size_t ws_size,
                              hipStream_t stream)
{
  const float* x     = (const float*)d_in[0];
  const float* Wq    = (const float*)d_in[1];
  const float* bq    = (const float*)d_in[2];
  const float* Wk    = (const float*)d_in[3];
  const float* bk    = (const float*)d_in[4];
  const float* Wv    = (const float*)d_in[5];
  const float* bv    = (const float*)d_in[6];
  const float* Wres  = (const float*)d_in[7];
  const float* bres  = (const float*)d_in[8];
  const float* gamma = (const float*)d_in[9];
  bf16_t* wsb = (bf16_t*)d_ws;                         // 81920 bf16 = 163840 B
  float*  bff = (float*)((char*)d_ws + BF_BYTE_OFF);   // + 1024 B
  float* out0 = (float*)d_out;                         // (8,256,256,18)
  float* out1 = out0 + (size_t)8 * 256 * 256 * 18;     // (8,256,256,256)

  prep_kernel<<<dim3(321), dim3(256), 0, stream>>>(Wq, Wk, Wv, bv, Wres, bres, wsb, bff);
  semwin_main<<<dim3(8192), dim3(256), 0, stream>>>(x, bq, bk, gamma, wsb, bff, out0, out1);
}